// Round 5
// baseline (8405.505 us; speedup 1.0000x reference)
//
#include <hip/hip_runtime.h>
#include <cmath>

#define NBLK 256
#define NTHR 512
#define SMEM_BYTES 18432

struct Args {
  const int* src; const int* tgt;
  const float* enc_emb;
  const float* enc_Wih; const float* enc_Whh; const float* enc_bih; const float* enc_bhh;
  const float* dec_emb;
  const float* dec_Wih; const float* dec_Whh; const float* dec_bih; const float* dec_bhh;
  const float* fc_W; const float* fc_b;
  float* out;
  unsigned* bar;                 // 8 counters (64B apart) + gen at +512B
  unsigned long long* gkeys;     // [8][64] argmax staging buckets
  float* h0[2]; float* h1[2];    // n-major h [64 n][512 m], ping-pong per layer
  float* seqT;                   // [64 t][64 n][512 m] encoder layer-0 outputs (n-major)
  float* fcWT;                   // [512][32000] transposed fc_W (optional)
  int use_wt;
};

// ---------------- grid barrier (round-4 version — proven) ----------------
__device__ __forceinline__ void gbar(unsigned* bar) {
  __syncthreads();
  if (threadIdx.x == 0) {
    unsigned* gen = bar + 128;
    unsigned g = __hip_atomic_load(gen, __ATOMIC_RELAXED, __HIP_MEMORY_SCOPE_AGENT);
    __hip_atomic_fetch_add(bar + (blockIdx.x & 7) * 16, 1u, __ATOMIC_RELEASE,
                           __HIP_MEMORY_SCOPE_AGENT);
    if (blockIdx.x == 0) {
      unsigned long long target = (unsigned long long)(g + 1) * NBLK;
      for (;;) {
        unsigned long long tot = 0;
#pragma unroll
        for (int i = 0; i < 8; ++i)
          tot += __hip_atomic_load(bar + i * 16, __ATOMIC_RELAXED,
                                   __HIP_MEMORY_SCOPE_AGENT);
        if (tot >= target) break;
      }
      __builtin_amdgcn_fence(__ATOMIC_ACQUIRE, "agent");
      __hip_atomic_fetch_add(gen, 1u, __ATOMIC_RELEASE, __HIP_MEMORY_SCOPE_AGENT);
    } else {
      while (__hip_atomic_load(gen, __ATOMIC_RELAXED, __HIP_MEMORY_SCOPE_AGENT) == g)
        __builtin_amdgcn_s_sleep(1);
      __builtin_amdgcn_fence(__ATOMIC_ACQUIRE, "agent");
    }
  }
  __syncthreads();
}

__device__ __forceinline__ float sigm(float x) { return 1.f / (1.f + expf(-x)); }

__device__ __forceinline__ unsigned long long packkey(float v, int j) {
  unsigned u = __float_as_uint(v);
  u = (u & 0x80000000u) ? ~u : (u | 0x80000000u);   // monotone float->uint
  return ((unsigned long long)u << 32) |
         (unsigned long long)(0xFFFFFFFFu - (unsigned)j);  // ties -> smallest j
}

__device__ __forceinline__ unsigned long long umaxll(unsigned long long a,
                                                     unsigned long long b) {
  return a > b ? a : b;
}

__device__ __forceinline__ void fma4(float x, float4 w, float* acc) {
  acc[0] = fmaf(x, w.x, acc[0]); acc[1] = fmaf(x, w.y, acc[1]);
  acc[2] = fmaf(x, w.z, acc[2]); acc[3] = fmaf(x, w.w, acc[3]);
}

// ---------------- bias load (16 floats into LDS) ----------------
__device__ void load_b(float* blds, int rbase,
                       const float* __restrict__ bih, const float* __restrict__ bhh)
{
  if (threadIdx.x < 8) {
    const int j = (threadIdx.x >> 1) * 512 + blockIdx.x * 2 + (threadIdx.x & 1);
    blds[rbase + threadIdx.x] = bih[j] + bhh[j];
  }
}

// ---------------- token resolve (into LDS) ----------------
__device__ void fill_tok(unsigned* toklds, const int* __restrict__ idx,
                         const unsigned long long* __restrict__ gkeys)
{
  if (threadIdx.x < 64) {
    unsigned row;
    if (idx) {
      row = (unsigned)idx[threadIdx.x];
    } else {
      unsigned long long best = gkeys[threadIdx.x];
#pragma unroll
      for (int i = 1; i < 8; ++i) best = umaxll(best, gkeys[i * 64 + threadIdx.x]);
      row = 0xFFFFFFFFu - (unsigned)best;
    }
    toklds[threadIdx.x] = row;
  }
  __syncthreads();
}

// ---------------- LSTM cell: register-streaming, LDS-free inner loop ----------------
// lane = n (batch row); wave wv slices k (chunk = it*64 + wv*8 .. +7).
// Each lane keeps x[n][k-chunk] and h[n][k-chunk] in registers (x via emb
// gather or n-major array, h via n-major array). Weights are streamed from
// GLOBAL memory with wave-uniform dwordx4 loads (L2-resident: 2 MB/XCD).
// Each weight element is read exactly once per cell per block. Per-wave
// partial z's reduce through zbuf (the only LDS use).
__device__ void cell(int gather, const float* __restrict__ xsrc,
                     const float* __restrict__ h_rd, float* __restrict__ h_wr,
                     const float* __restrict__ Wih, const float* __restrict__ Whh,
                     int rbase, float* __restrict__ cl,
                     float* __restrict__ seq_out,
                     const float* __restrict__ blds, float* __restrict__ zbuf,
                     const unsigned* __restrict__ toklds)
{
  const int tid = threadIdx.x;
  const int lane = tid & 63, wv = tid >> 6;
  const int bid2 = blockIdx.x * 2;
  const float* xs = gather ? xsrc + (size_t)toklds[lane] * 512
                           : xsrc + (size_t)lane * 512;
  const float* hs = h_rd + (size_t)lane * 512;

  float acc[8] = {0.f, 0.f, 0.f, 0.f, 0.f, 0.f, 0.f, 0.f};
  const int k0 = wv * 8;
  float4 xa0 = *(const float4*)(xs + k0), xa1 = *(const float4*)(xs + k0 + 4);
  float4 ha0 = *(const float4*)(hs + k0), ha1 = *(const float4*)(hs + k0 + 4);

#pragma unroll 1
  for (int it = 0; it < 8; ++it) {
    const int kc = it * 64 + k0;
    float4 xb0, xb1, hb0, hb1;
    if (it < 7) {                       // prefetch next chunk (latency-tolerant)
      xb0 = *(const float4*)(xs + kc + 64); xb1 = *(const float4*)(xs + kc + 68);
      hb0 = *(const float4*)(hs + kc + 64); hb1 = *(const float4*)(hs + kc + 68);
    }
#pragma unroll
    for (int r = 0; r < 8; ++r) {
      const size_t j = (size_t)((r >> 1) * 512 + bid2 + (r & 1));
      const float* wi = Wih + j * 512 + kc;   // wave-uniform addresses
      const float* wh = Whh + j * 512 + kc;
      float4 w0 = *(const float4*)wi, w1 = *(const float4*)(wi + 4);
      float4 u0 = *(const float4*)wh, u1 = *(const float4*)(wh + 4);
      float s = acc[r];
      s = fmaf(w0.x, xa0.x, s); s = fmaf(w0.y, xa0.y, s);
      s = fmaf(w0.z, xa0.z, s); s = fmaf(w0.w, xa0.w, s);
      s = fmaf(w1.x, xa1.x, s); s = fmaf(w1.y, xa1.y, s);
      s = fmaf(w1.z, xa1.z, s); s = fmaf(w1.w, xa1.w, s);
      s = fmaf(u0.x, ha0.x, s); s = fmaf(u0.y, ha0.y, s);
      s = fmaf(u0.z, ha0.z, s); s = fmaf(u0.w, ha0.w, s);
      s = fmaf(u1.x, ha1.x, s); s = fmaf(u1.y, ha1.y, s);
      s = fmaf(u1.z, ha1.z, s); s = fmaf(u1.w, ha1.w, s);
      acc[r] = s;
    }
    if (it < 7) { xa0 = xb0; xa1 = xb1; ha0 = hb0; ha1 = hb1; }
  }
#pragma unroll
  for (int r = 0; r < 8; ++r)
    zbuf[wv * 512 + r * 64 + lane] = acc[r];
  __syncthreads();
  if (tid < 128) {
    const int mloc = tid >> 6, n = tid & 63;
    float z[4];
#pragma unroll
    for (int g = 0; g < 4; ++g) {
      const int r = g * 2 + mloc;
      float s = blds[rbase + r];
#pragma unroll
      for (int w = 0; w < 8; ++w) s += zbuf[w * 512 + r * 64 + n];
      z[g] = s;
    }
    float ig = sigm(z[0]), fg = sigm(z[1]);
    float gg = tanhf(z[2]), og = sigm(z[3]);
    const int m = bid2 + mloc;
    float cc = fg * cl[mloc * 64 + n] + ig * gg;
    cl[mloc * 64 + n] = cc;
    float hh = og * tanhf(cc);
    h_wr[(size_t)n * 512 + m] = hh;                       // n-major state
    if (seq_out) seq_out[(size_t)n * 512 + m] = hh;       // n-major seq
  }
  __syncthreads();   // zbuf safe for next cell in same phase
}

// ---------------- fc (vocab projection) + fused argmax ----------------
__device__ void fc_phase(unsigned long long* skeys, int d,
                         const float* __restrict__ h,
                         const float* __restrict__ fcW,
                         const float* __restrict__ fcWT, int use_wt,
                         const float* __restrict__ fcb,
                         float* __restrict__ out,
                         unsigned long long* __restrict__ gkeys, int do_arg)
{
  const int tid = threadIdx.x, bid = blockIdx.x;
  if (do_arg && tid < 64) skeys[tid] = 0ULL;
  __syncthreads();
  if (bid < 250) {
    const int jt = tid & 31, nt = tid >> 5;
    const int j0 = bid * 128 + jt * 4;
    const int n0 = nt * 4;
    float acc[4][4] = {};
    if (use_wt) {
      const float* wt = fcWT + j0;
#pragma unroll 2
      for (int k = 0; k < 512; k += 8) {
        float4 wv[8];
#pragma unroll
        for (int i = 0; i < 8; ++i)
          wv[i] = *(const float4*)(wt + (size_t)(k + i) * 32000);
        float4 ha[4], hb[4];
#pragma unroll
        for (int ni = 0; ni < 4; ++ni) {
          ha[ni] = *(const float4*)(h + (size_t)(n0 + ni) * 512 + k);
          hb[ni] = *(const float4*)(h + (size_t)(n0 + ni) * 512 + k + 4);
        }
#pragma unroll
        for (int ni = 0; ni < 4; ++ni) {
          fma4(ha[ni].x, wv[0], acc[ni]); fma4(ha[ni].y, wv[1], acc[ni]);
          fma4(ha[ni].z, wv[2], acc[ni]); fma4(ha[ni].w, wv[3], acc[ni]);
          fma4(hb[ni].x, wv[4], acc[ni]); fma4(hb[ni].y, wv[5], acc[ni]);
          fma4(hb[ni].z, wv[6], acc[ni]); fma4(hb[ni].w, wv[7], acc[ni]);
        }
      }
    } else {
#pragma unroll 2
      for (int k = 0; k < 512; k += 8) {
        float4 wr[4][2];
#pragma unroll
        for (int i = 0; i < 4; ++i) {
          wr[i][0] = *(const float4*)(fcW + (size_t)(j0 + i) * 512 + k);
          wr[i][1] = *(const float4*)(fcW + (size_t)(j0 + i) * 512 + k + 4);
        }
        float4 ha[4], hb[4];
#pragma unroll
        for (int ni = 0; ni < 4; ++ni) {
          ha[ni] = *(const float4*)(h + (size_t)(n0 + ni) * 512 + k);
          hb[ni] = *(const float4*)(h + (size_t)(n0 + ni) * 512 + k + 4);
        }
#pragma unroll
        for (int ni = 0; ni < 4; ++ni) {
#pragma unroll
          for (int ji = 0; ji < 4; ++ji) {
            float s = acc[ni][ji];
            s = fmaf(ha[ni].x, wr[ji][0].x, s); s = fmaf(ha[ni].y, wr[ji][0].y, s);
            s = fmaf(ha[ni].z, wr[ji][0].z, s); s = fmaf(ha[ni].w, wr[ji][0].w, s);
            s = fmaf(hb[ni].x, wr[ji][1].x, s); s = fmaf(hb[ni].y, wr[ji][1].y, s);
            s = fmaf(hb[ni].z, wr[ji][1].z, s); s = fmaf(hb[ni].w, wr[ji][1].w, s);
            acc[ni][ji] = s;
          }
        }
      }
    }
    const float b0 = fcb[j0], b1 = fcb[j0 + 1], b2 = fcb[j0 + 2], b3 = fcb[j0 + 3];
#pragma unroll
    for (int ni = 0; ni < 4; ++ni) {
      const int n = n0 + ni;
      float4 v = make_float4(acc[ni][0] + b0, acc[ni][1] + b1,
                             acc[ni][2] + b2, acc[ni][3] + b3);
      *(float4*)(out + ((size_t)(d + 1) * 64 + n) * 32000 + j0) = v;
      if (do_arg) {
        unsigned long long kb = umaxll(umaxll(packkey(v.x, j0), packkey(v.y, j0 + 1)),
                                       umaxll(packkey(v.z, j0 + 2), packkey(v.w, j0 + 3)));
        atomicMax(&skeys[n], kb);
      }
    }
  }
  __syncthreads();
  if (do_arg && bid < 250 && tid < 64)
    atomicMax(&gkeys[(bid & 7) * 64 + tid], skeys[tid]);
}

// ---------------- fc_W transpose: [32000][512] -> [512][32000] ----------------
__global__ void __launch_bounds__(256) fc_transpose(const float* __restrict__ W,
                                                    float* __restrict__ WT)
{
  __shared__ float tile[64][65];
  const int jb = blockIdx.x * 64;
  const int kb = blockIdx.y * 64;
  const int t = threadIdx.x;
  const int row = t >> 2, seg = t & 3;
  const float* src = W + (size_t)(jb + row) * 512 + kb + seg * 16;
#pragma unroll
  for (int i = 0; i < 4; ++i) {
    float4 v = *(const float4*)(src + i * 4);
    tile[row][seg * 16 + i * 4 + 0] = v.x;
    tile[row][seg * 16 + i * 4 + 1] = v.y;
    tile[row][seg * 16 + i * 4 + 2] = v.z;
    tile[row][seg * 16 + i * 4 + 3] = v.w;
  }
  __syncthreads();
  float* dst = WT + (size_t)(kb + row) * 32000 + jb + seg * 16;
#pragma unroll
  for (int i = 0; i < 4; ++i) {
    float4 v = make_float4(tile[seg * 16 + i * 4 + 0][row], tile[seg * 16 + i * 4 + 1][row],
                           tile[seg * 16 + i * 4 + 2][row], tile[seg * 16 + i * 4 + 3][row]);
    *(float4*)(dst + i * 4) = v;
  }
}

// ---------------- fused everything kernel ----------------
extern "C" __global__ void __launch_bounds__(NTHR, 2)
s2s_main(Args a)
{
  extern __shared__ float smem[];
  float* zbuf = smem;                                   // [8 wv][8 r][64 n] = 4096 f
  float* blds = zbuf + 4096;                            // 16
  float* clds = blds + 16;                              // [2 layer][2 mloc][64 n] = 256
  unsigned* toklds = (unsigned*)(clds + 256);           // 64 u32
  unsigned long long* skeys = (unsigned long long*)(toklds + 64);  // 64 u64

  const int tid = threadIdx.x;

  // ---- encoder: wavefront-pipelined (l0[t] + l1[t-1] per phase) ----
  load_b(blds, 0, a.enc_bih, a.enc_bhh);
  load_b(blds, 8, a.enc_bih + 2048, a.enc_bhh + 2048);
  if (tid < 256) clds[tid] = 0.f;
  __syncthreads();
  const float* E1i = a.enc_Wih + (size_t)2048 * 512;
  const float* E1h = a.enc_Whh + (size_t)2048 * 512;
  int p0 = 0, p1 = 0;
#pragma unroll 1
  for (int t = 0; t < 65; ++t) {
    if (t < 64) {
      fill_tok(toklds, a.src + t * 64, nullptr);
      cell(1, a.enc_emb, a.h0[p0], a.h0[p0 ^ 1], a.enc_Wih, a.enc_Whh, 0, clds,
           a.seqT + (size_t)t * 32768, blds, zbuf, toklds);
      p0 ^= 1;
    }
    if (t >= 1) {
      cell(0, a.seqT + (size_t)(t - 1) * 32768, a.h1[p1], a.h1[p1 ^ 1], E1i, E1h, 8,
           clds + 128, nullptr, blds, zbuf, toklds);
      p1 ^= 1;
    }
    gbar(a.bar);
  }
  // ---- decoder ----
  load_b(blds, 0, a.dec_bih, a.dec_bhh);
  load_b(blds, 8, a.dec_bih + 2048, a.dec_bhh + 2048);
  const float* D1i = a.dec_Wih + (size_t)2048 * 512;
  const float* D1h = a.dec_Whh + (size_t)2048 * 512;
#pragma unroll 1
  for (int d = 0; d < 31; ++d) {
    fill_tok(toklds, d == 0 ? a.tgt : nullptr, a.gkeys);
    cell(1, a.dec_emb, a.h0[p0], a.h0[p0 ^ 1], a.dec_Wih, a.dec_Whh, 0, clds,
         nullptr, blds, zbuf, toklds);
    p0 ^= 1;
    gbar(a.bar);
    if (blockIdx.x == 0) a.gkeys[tid] = 0ULL;   // reset buckets for this step's fc
    cell(0, a.h0[p0], a.h1[p1], a.h1[p1 ^ 1], D1i, D1h, 8, clds + 128,
         nullptr, blds, zbuf, toklds);
    p1 ^= 1;
    gbar(a.bar);
    fc_phase(skeys, d, a.h1[p1], a.fc_W, a.fcWT, a.use_wt, a.fc_b, a.out, a.gkeys, d < 30);
    if (d < 30) gbar(a.bar);
  }
}

extern "C" void kernel_launch(void* const* d_in, const int* in_sizes, int n_in,
                              void* d_out, int out_size, void* d_ws, size_t ws_size,
                              hipStream_t stream)
{
  (void)in_sizes; (void)n_in; (void)out_size;
  Args a;
  a.src     = (const int*)d_in[0];
  a.tgt     = (const int*)d_in[1];
  a.enc_emb = (const float*)d_in[2];
  a.enc_Wih = (const float*)d_in[3];
  a.enc_Whh = (const float*)d_in[4];
  a.enc_bih = (const float*)d_in[5];
  a.enc_bhh = (const float*)d_in[6];
  a.dec_emb = (const float*)d_in[7];
  a.dec_Wih = (const float*)d_in[8];
  a.dec_Whh = (const float*)d_in[9];
  a.dec_bih = (const float*)d_in[10];
  a.dec_bhh = (const float*)d_in[11];
  a.fc_W    = (const float*)d_in[12];
  a.fc_b    = (const float*)d_in[13];
  a.out     = (float*)d_out;

  char* ws = (char*)d_ws;
  a.bar   = (unsigned*)ws;                         // 1 KB
  a.gkeys = (unsigned long long*)(ws + 1024);      // 4 KB (512 u64)
  float* f = (float*)(ws + 8192);
  a.h0[0] = f;                // 32768 floats each ([64][512] n-major)
  a.h0[1] = f + 32768;
  a.h1[0] = f + 65536;
  a.h1[1] = f + 98304;
  a.seqT  = f + 131072;       // 64*32768 = 2097152 floats (n-major per step)
  size_t base_f = 131072 + 2097152;
  a.fcWT = nullptr; a.use_wt = 0;
  size_t wt_need = 8192 + (base_f + (size_t)512 * 32000) * 4;
  if (ws_size >= wt_need) { a.fcWT = f + base_f; a.use_wt = 1; }

  hipFuncSetAttribute((const void*)s2s_main,
                      hipFuncAttributeMaxDynamicSharedMemorySize, SMEM_BYTES);

  // zero barrier/gkeys/h state and the t=0 output slice
  hipMemsetAsync(d_ws, 0, 8192 + (size_t)131072 * 4, stream);
  hipMemsetAsync(d_out, 0, (size_t)64 * 32000 * 4, stream);
  if (a.use_wt)
    fc_transpose<<<dim3(500, 8), 256, 0, stream>>>(a.fc_W, a.fcWT);

  void* params[] = {&a};
  hipLaunchCooperativeKernel((const void*)s2s_main, dim3(NBLK), dim3(NTHR),
                             params, SMEM_BYTES, stream);
}

// Round 6
// 6469.948 us; speedup vs baseline: 1.2992x; 1.2992x over previous
//
#include <hip/hip_runtime.h>
#include <cmath>

#define NBLK 256
#define NTHR 512
#define SMEM_BYTES 149312

struct Args {
  const int* src; const int* tgt;
  const float* enc_emb;
  const float* enc_Wih; const float* enc_Whh; const float* enc_bih; const float* enc_bhh;
  const float* dec_emb;
  const float* dec_Wih; const float* dec_Whh; const float* dec_bih; const float* dec_bhh;
  const float* fc_W; const float* fc_b;
  float* out;
  unsigned* bar;                 // 8 counters (64B apart) + gen at +512B
  unsigned long long* gkeys;     // [8][64] argmax staging buckets
  float* hT0[2]; float* hT1[2];  // transposed h [512 m][64 n], ping-pong per layer
  float* hnm;                    // n-major h of dec-l1 for fc [64][512]
  float* seqT;                   // [64 t][512 m][64 n] encoder layer-0 outputs
  float* fcWT;                   // [512][32000] transposed fc_W (optional)
  int use_wt;
};

// ---------------- grid barrier (round-4 version — proven) ----------------
__device__ __forceinline__ void gbar(unsigned* bar) {
  __syncthreads();
  if (threadIdx.x == 0) {
    unsigned* gen = bar + 128;
    unsigned g = __hip_atomic_load(gen, __ATOMIC_RELAXED, __HIP_MEMORY_SCOPE_AGENT);
    __hip_atomic_fetch_add(bar + (blockIdx.x & 7) * 16, 1u, __ATOMIC_RELEASE,
                           __HIP_MEMORY_SCOPE_AGENT);
    if (blockIdx.x == 0) {
      unsigned long long target = (unsigned long long)(g + 1) * NBLK;
      for (;;) {
        unsigned long long tot = 0;
#pragma unroll
        for (int i = 0; i < 8; ++i)
          tot += __hip_atomic_load(bar + i * 16, __ATOMIC_RELAXED,
                                   __HIP_MEMORY_SCOPE_AGENT);
        if (tot >= target) break;
      }
      __builtin_amdgcn_fence(__ATOMIC_ACQUIRE, "agent");
      __hip_atomic_fetch_add(gen, 1u, __ATOMIC_RELEASE, __HIP_MEMORY_SCOPE_AGENT);
    } else {
      while (__hip_atomic_load(gen, __ATOMIC_RELAXED, __HIP_MEMORY_SCOPE_AGENT) == g)
        __builtin_amdgcn_s_sleep(1);
      __builtin_amdgcn_fence(__ATOMIC_ACQUIRE, "agent");
    }
  }
  __syncthreads();
}

__device__ __forceinline__ float sigm(float x) { return 1.f / (1.f + expf(-x)); }

__device__ __forceinline__ unsigned long long packkey(float v, int j) {
  unsigned u = __float_as_uint(v);
  u = (u & 0x80000000u) ? ~u : (u | 0x80000000u);   // monotone float->uint
  return ((unsigned long long)u << 32) |
         (unsigned long long)(0xFFFFFFFFu - (unsigned)j);  // ties -> smallest j
}

__device__ __forceinline__ unsigned long long umaxll(unsigned long long a,
                                                     unsigned long long b) {
  return a > b ? a : b;
}

__device__ __forceinline__ void fma4(float x, float4 w, float* acc) {
  acc[0] = fmaf(x, w.x, acc[0]); acc[1] = fmaf(x, w.y, acc[1]);
  acc[2] = fmaf(x, w.z, acc[2]); acc[3] = fmaf(x, w.w, acc[3]);
}

// ---------------- weight load into LDS (8 rows of [Wih(512)|Whh(512)]) ----------------
__device__ void load_w(float* wlds, float* blds, int rbase,
                       const float* __restrict__ Wih, const float* __restrict__ Whh,
                       const float* __restrict__ bih, const float* __restrict__ bhh)
{
  const int tid = threadIdx.x, bid = blockIdx.x;
  for (int idx = tid; idx < 8 * 256; idx += NTHR) {
    const int r = idx >> 8, c = idx & 255;
    const int j = (r >> 1) * 512 + bid * 2 + (r & 1);
    float4 v;
    if (c < 128) v = *(const float4*)(Wih + (size_t)j * 512 + c * 4);
    else         v = *(const float4*)(Whh + (size_t)j * 512 + (c - 128) * 4);
    *(float4*)(wlds + (size_t)(rbase + r) * 1024 + c * 4) = v;
  }
  if (tid < 8) {
    const int j = (tid >> 1) * 512 + bid * 2 + (tid & 1);
    blds[rbase + tid] = bih[j] + bhh[j];
  }
}

// ---------------- token resolve (into LDS) ----------------
__device__ void fill_tok(unsigned* toklds, const int* __restrict__ idx,
                         const unsigned long long* __restrict__ gkeys)
{
  if (threadIdx.x < 64) {
    unsigned row;
    if (idx) {
      row = (unsigned)idx[threadIdx.x];
    } else {
      unsigned long long best = gkeys[threadIdx.x];
#pragma unroll
      for (int i = 1; i < 8; ++i) best = umaxll(best, gkeys[i * 64 + threadIdx.x]);
      row = 0xFFFFFFFFu - (unsigned)best;
    }
    toklds[threadIdx.x] = row;
  }
  __syncthreads();
}

// ---------------- LSTM cell: transposed, LDS-resident ----------------
// v6 remap: wave wv owns a 16-wide combined-k slice per it (waves 0-3 -> x
// slice, waves 4-7 -> h slice) and computes ALL 8 gate-rows over it. Each
// staged value is read ONCE (1024 b32/block-cell vs round-4's 4096); weight
// b128 broadcasts unchanged (2048, each weight read once). Staging, layouts,
// and epilogue gate math are round-4 verbatim; per-wave partials (8 accs)
// reduce 8-way through zbuf.
__device__ void cell(int gather, const float* __restrict__ xsrc,
                     const float* __restrict__ hT_rd, float* __restrict__ hT_wr,
                     int wrow0, float* __restrict__ cl,
                     float* __restrict__ seqT_out, float* __restrict__ hnm_out,
                     const float* __restrict__ wlds, const float* __restrict__ blds,
                     float* __restrict__ tiles, float* __restrict__ zbuf,
                     const unsigned* __restrict__ toklds)
{
  const int tid = threadIdx.x;
  const int lane = tid & 63, wv = tid >> 6;
  // value-slice base in tile; weight column base (+ it*64 each iteration)
  const int vbase = (wv < 4) ? wv * 1024 : 4096 + (wv - 4) * 1024;  // 16 k * 64 n
  const int wcol0 = (wv < 4) ? wv * 16 : 512 + (wv - 4) * 16;
  const float* wrow = wlds + (size_t)wrow0 * 1024 + wcol0;
  float acc[8] = {0.f, 0.f, 0.f, 0.f, 0.f, 0.f, 0.f, 0.f};
  float4 rg0, rg1, rg2, rg3;

  // load iteration's staging data into registers (global loads, latency-tolerant)
  auto load_iter = [&](int it) {
    if (gather) {
      unsigned row = toklds[lane];
      const float* er = xsrc + (size_t)row * 512 + it * 64 + wv * 8;
      rg0 = *(const float4*)er;
      rg1 = *(const float4*)(er + 4);
      const float* hs = hT_rd + it * 4096 + wv * 512 + lane * 4;
      rg2 = *(const float4*)hs;
      rg3 = *(const float4*)(hs + 256);
    } else {
      const float* s = (wv < 4) ? (xsrc + it * 4096 + wv * 1024 + lane * 4)
                                : (hT_rd + it * 4096 + (wv - 4) * 1024 + lane * 4);
      rg0 = *(const float4*)s;
      rg1 = *(const float4*)(s + 256);
      rg2 = *(const float4*)(s + 512);
      rg3 = *(const float4*)(s + 768);
    }
  };
  // commit registers to LDS tile buffer
  auto commit_iter = [&](int buf) {
    float* tb = tiles + buf * 8192;
    if (gather) {
      float* tx = tb + (wv * 8) * 64 + lane;               // transpose x rows
      tx[0]   = rg0.x; tx[64]  = rg0.y; tx[128] = rg0.z; tx[192] = rg0.w;
      tx[256] = rg1.x; tx[320] = rg1.y; tx[384] = rg1.z; tx[448] = rg1.w;
      float* th = tb + 4096 + wv * 512 + lane * 4;         // h is already transposed
      *(float4*)th = rg2;
      *(float4*)(th + 256) = rg3;
    } else {
      float* t0 = tb + wv * 1024 + lane * 4;
      *(float4*)t0 = rg0;
      *(float4*)(t0 + 256) = rg1;
      *(float4*)(t0 + 512) = rg2;
      *(float4*)(t0 + 768) = rg3;
    }
  };

  load_iter(0);
  commit_iter(0);
#pragma unroll 1
  for (int it = 0; it < 8; ++it) {
    __syncthreads();                       // tile(it) staged by all waves
    if (it < 7) load_iter(it + 1);         // issue next global loads early
    const float* tp = tiles + (it & 1) * 8192 + vbase + lane;
    const float* wb = wrow + it * 64;
    float val[16];
#pragma unroll
    for (int j = 0; j < 16; ++j) val[j] = tp[j * 64];   // each value read once
#pragma unroll
    for (int jq = 0; jq < 4; ++jq) {
#pragma unroll
      for (int r = 0; r < 8; ++r) {
        float4 w = *(const float4*)(wb + r * 1024 + jq * 4);  // uniform broadcast
        float s = acc[r];
        s = fmaf(w.x, val[jq * 4 + 0], s); s = fmaf(w.y, val[jq * 4 + 1], s);
        s = fmaf(w.z, val[jq * 4 + 2], s); s = fmaf(w.w, val[jq * 4 + 3], s);
        acc[r] = s;
      }
    }
    if (it < 7) commit_iter((it + 1) & 1);
  }
#pragma unroll
  for (int r = 0; r < 8; ++r)
    zbuf[wv * 512 + r * 64 + lane] = acc[r];
  __syncthreads();
  if (tid < 128) {
    const int mloc = tid >> 6, n = tid & 63;
    float z[4];
#pragma unroll
    for (int g = 0; g < 4; ++g) {
      const int r = g * 2 + mloc;
      float s = blds[wrow0 + r];
#pragma unroll
      for (int w = 0; w < 8; ++w) s += zbuf[w * 512 + r * 64 + n];
      z[g] = s;
    }
    float ig = sigm(z[0]), fg = sigm(z[1]);
    float gg = tanhf(z[2]), og = sigm(z[3]);
    const int m = blockIdx.x * 2 + mloc;
    float cc = fg * cl[mloc * 64 + n] + ig * gg;
    cl[mloc * 64 + n] = cc;
    float hh = og * tanhf(cc);
    hT_wr[m * 64 + n] = hh;
    if (seqT_out) seqT_out[m * 64 + n] = hh;
    if (hnm_out) hnm_out[n * 512 + m] = hh;
  }
}

// ---------------- fc (vocab projection) + fused argmax ----------------
__device__ void fc_phase(unsigned long long* skeys, int d,
                         const float* __restrict__ h,
                         const float* __restrict__ fcW,
                         const float* __restrict__ fcWT, int use_wt,
                         const float* __restrict__ fcb,
                         float* __restrict__ out,
                         unsigned long long* __restrict__ gkeys, int do_arg)
{
  const int tid = threadIdx.x, bid = blockIdx.x;
  if (do_arg && tid < 64) skeys[tid] = 0ULL;
  __syncthreads();
  if (bid < 250) {
    const int jt = tid & 31, nt = tid >> 5;
    const int j0 = bid * 128 + jt * 4;
    const int n0 = nt * 4;
    float acc[4][4] = {};
    if (use_wt) {
      const float* wt = fcWT + j0;
#pragma unroll 2
      for (int k = 0; k < 512; k += 8) {
        float4 wv[8];
#pragma unroll
        for (int i = 0; i < 8; ++i)
          wv[i] = *(const float4*)(wt + (size_t)(k + i) * 32000);
        float4 ha[4], hb[4];
#pragma unroll
        for (int ni = 0; ni < 4; ++ni) {
          ha[ni] = *(const float4*)(h + (size_t)(n0 + ni) * 512 + k);
          hb[ni] = *(const float4*)(h + (size_t)(n0 + ni) * 512 + k + 4);
        }
#pragma unroll
        for (int ni = 0; ni < 4; ++ni) {
          fma4(ha[ni].x, wv[0], acc[ni]); fma4(ha[ni].y, wv[1], acc[ni]);
          fma4(ha[ni].z, wv[2], acc[ni]); fma4(ha[ni].w, wv[3], acc[ni]);
          fma4(hb[ni].x, wv[4], acc[ni]); fma4(hb[ni].y, wv[5], acc[ni]);
          fma4(hb[ni].z, wv[6], acc[ni]); fma4(hb[ni].w, wv[7], acc[ni]);
        }
      }
    } else {
#pragma unroll 2
      for (int k = 0; k < 512; k += 8) {
        float4 wr[4][2];
#pragma unroll
        for (int i = 0; i < 4; ++i) {
          wr[i][0] = *(const float4*)(fcW + (size_t)(j0 + i) * 512 + k);
          wr[i][1] = *(const float4*)(fcW + (size_t)(j0 + i) * 512 + k + 4);
        }
        float4 ha[4], hb[4];
#pragma unroll
        for (int ni = 0; ni < 4; ++ni) {
          ha[ni] = *(const float4*)(h + (size_t)(n0 + ni) * 512 + k);
          hb[ni] = *(const float4*)(h + (size_t)(n0 + ni) * 512 + k + 4);
        }
#pragma unroll
        for (int ni = 0; ni < 4; ++ni) {
#pragma unroll
          for (int ji = 0; ji < 4; ++ji) {
            float s = acc[ni][ji];
            s = fmaf(ha[ni].x, wr[ji][0].x, s); s = fmaf(ha[ni].y, wr[ji][0].y, s);
            s = fmaf(ha[ni].z, wr[ji][0].z, s); s = fmaf(ha[ni].w, wr[ji][0].w, s);
            s = fmaf(hb[ni].x, wr[ji][1].x, s); s = fmaf(hb[ni].y, wr[ji][1].y, s);
            s = fmaf(hb[ni].z, wr[ji][1].z, s); s = fmaf(hb[ni].w, wr[ji][1].w, s);
            acc[ni][ji] = s;
          }
        }
      }
    }
    const float b0 = fcb[j0], b1 = fcb[j0 + 1], b2 = fcb[j0 + 2], b3 = fcb[j0 + 3];
#pragma unroll
    for (int ni = 0; ni < 4; ++ni) {
      const int n = n0 + ni;
      float4 v = make_float4(acc[ni][0] + b0, acc[ni][1] + b1,
                             acc[ni][2] + b2, acc[ni][3] + b3);
      *(float4*)(out + ((size_t)(d + 1) * 64 + n) * 32000 + j0) = v;
      if (do_arg) {
        unsigned long long kb = umaxll(umaxll(packkey(v.x, j0), packkey(v.y, j0 + 1)),
                                       umaxll(packkey(v.z, j0 + 2), packkey(v.w, j0 + 3)));
        atomicMax(&skeys[n], kb);
      }
    }
  }
  __syncthreads();
  if (do_arg && bid < 250 && tid < 64)
    atomicMax(&gkeys[(bid & 7) * 64 + tid], skeys[tid]);
}

// ---------------- fc_W transpose: [32000][512] -> [512][32000] ----------------
__global__ void __launch_bounds__(256) fc_transpose(const float* __restrict__ W,
                                                    float* __restrict__ WT)
{
  __shared__ float tile[64][65];
  const int jb = blockIdx.x * 64;
  const int kb = blockIdx.y * 64;
  const int t = threadIdx.x;
  const int row = t >> 2, seg = t & 3;
  const float* src = W + (size_t)(jb + row) * 512 + kb + seg * 16;
#pragma unroll
  for (int i = 0; i < 4; ++i) {
    float4 v = *(const float4*)(src + i * 4);
    tile[row][seg * 16 + i * 4 + 0] = v.x;
    tile[row][seg * 16 + i * 4 + 1] = v.y;
    tile[row][seg * 16 + i * 4 + 2] = v.z;
    tile[row][seg * 16 + i * 4 + 3] = v.w;
  }
  __syncthreads();
  float* dst = WT + (size_t)(kb + row) * 32000 + jb + seg * 16;
#pragma unroll
  for (int i = 0; i < 4; ++i) {
    float4 v = make_float4(tile[seg * 16 + i * 4 + 0][row], tile[seg * 16 + i * 4 + 1][row],
                           tile[seg * 16 + i * 4 + 2][row], tile[seg * 16 + i * 4 + 3][row]);
    *(float4*)(dst + i * 4) = v;
  }
}

// ---------------- fused everything kernel ----------------
extern "C" __global__ void __launch_bounds__(NTHR, 2)
s2s_main(Args a)
{
  extern __shared__ float smem[];
  float* wlds  = smem;                    // 16 rows x 1024 = 16384 f (64 KB)
  float* tiles = wlds + 16384;            // 2 bufs x (x-tile 4096 + h-tile 4096) = 16384 f
  float* zbuf  = tiles + 16384;           // [8 wv][8 r][64 n] = 4096 f
  float* blds  = zbuf + 4096;             // 16
  float* clds  = blds + 16;               // [2 layer][2 mloc][64 n] = 256
  unsigned* toklds = (unsigned*)(clds + 256);          // 64 u32
  unsigned long long* skeys = (unsigned long long*)(toklds + 64);  // 64 u64

  const int tid = threadIdx.x;

  // ---- encoder: both layers' weights resident; wavefront-pipelined ----
  load_w(wlds, blds, 0, a.enc_Wih, a.enc_Whh, a.enc_bih, a.enc_bhh);
  load_w(wlds, blds, 8, a.enc_Wih + (size_t)2048 * 512, a.enc_Whh + (size_t)2048 * 512,
         a.enc_bih + 2048, a.enc_bhh + 2048);
  if (tid < 256) clds[tid] = 0.f;
  __syncthreads();
  int p0 = 0, p1 = 0;
#pragma unroll 1
  for (int t = 0; t < 65; ++t) {
    if (t < 64) {
      fill_tok(toklds, a.src + t * 64, nullptr);
      cell(1, a.enc_emb, a.hT0[p0], a.hT0[p0 ^ 1], 0, clds,
           a.seqT + (size_t)t * 32768, nullptr, wlds, blds, tiles, zbuf, toklds);
      p0 ^= 1;
    }
    if (t >= 1) {
      cell(0, a.seqT + (size_t)(t - 1) * 32768, a.hT1[p1], a.hT1[p1 ^ 1], 8, clds + 128,
           nullptr, nullptr, wlds, blds, tiles, zbuf, toklds);
      p1 ^= 1;
    }
    gbar(a.bar);
  }
  // ---- decoder: both layers' weights resident ----
  load_w(wlds, blds, 0, a.dec_Wih, a.dec_Whh, a.dec_bih, a.dec_bhh);
  load_w(wlds, blds, 8, a.dec_Wih + (size_t)2048 * 512, a.dec_Whh + (size_t)2048 * 512,
         a.dec_bih + 2048, a.dec_bhh + 2048);
  __syncthreads();
#pragma unroll 1
  for (int d = 0; d < 31; ++d) {
    fill_tok(toklds, d == 0 ? a.tgt : nullptr, a.gkeys);
    cell(1, a.dec_emb, a.hT0[p0], a.hT0[p0 ^ 1], 0, clds,
         nullptr, nullptr, wlds, blds, tiles, zbuf, toklds);
    p0 ^= 1;
    gbar(a.bar);
    if (blockIdx.x == 0) a.gkeys[tid] = 0ULL;   // reset buckets for this step's fc
    cell(0, a.hT0[p0], a.hT1[p1], a.hT1[p1 ^ 1], 8, clds + 128,
         nullptr, a.hnm, wlds, blds, tiles, zbuf, toklds);
    p1 ^= 1;
    gbar(a.bar);
    fc_phase(skeys, d, a.hnm, a.fc_W, a.fcWT, a.use_wt, a.fc_b, a.out, a.gkeys, d < 30);
    if (d < 30) gbar(a.bar);
  }
}

extern "C" void kernel_launch(void* const* d_in, const int* in_sizes, int n_in,
                              void* d_out, int out_size, void* d_ws, size_t ws_size,
                              hipStream_t stream)
{
  (void)in_sizes; (void)n_in; (void)out_size;
  Args a;
  a.src     = (const int*)d_in[0];
  a.tgt     = (const int*)d_in[1];
  a.enc_emb = (const float*)d_in[2];
  a.enc_Wih = (const float*)d_in[3];
  a.enc_Whh = (const float*)d_in[4];
  a.enc_bih = (const float*)d_in[5];
  a.enc_bhh = (const float*)d_in[6];
  a.dec_emb = (const float*)d_in[7];
  a.dec_Wih = (const float*)d_in[8];
  a.dec_Whh = (const float*)d_in[9];
  a.dec_bih = (const float*)d_in[10];
  a.dec_bhh = (const float*)d_in[11];
  a.fc_W    = (const float*)d_in[12];
  a.fc_b    = (const float*)d_in[13];
  a.out     = (float*)d_out;

  char* ws = (char*)d_ws;
  a.bar   = (unsigned*)ws;                         // 1 KB
  a.gkeys = (unsigned long long*)(ws + 1024);      // 4 KB (512 u64)
  float* f = (float*)(ws + 8192);
  a.hT0[0] = f;               // 32768 each
  a.hT0[1] = f + 32768;
  a.hT1[0] = f + 65536;
  a.hT1[1] = f + 98304;
  a.hnm    = f + 131072;      // 32768
  a.seqT   = f + 163840;      // 64*32768 = 2097152
  size_t base_f = 163840 + 2097152;
  a.fcWT = nullptr; a.use_wt = 0;
  size_t wt_need = 8192 + (base_f + (size_t)512 * 32000) * 4;
  if (ws_size >= wt_need) { a.fcWT = f + base_f; a.use_wt = 1; }

  hipFuncSetAttribute((const void*)s2s_main,
                      hipFuncAttributeMaxDynamicSharedMemorySize, SMEM_BYTES);

  // zero barrier/gkeys/hT state and the t=0 output slice
  hipMemsetAsync(d_ws, 0, 8192 + (size_t)131072 * 4, stream);
  hipMemsetAsync(d_out, 0, (size_t)64 * 32000 * 4, stream);
  if (a.use_wt)
    fc_transpose<<<dim3(500, 8), 256, 0, stream>>>(a.fc_W, a.fcWT);

  void* params[] = {&a};
  hipLaunchCooperativeKernel((const void*)s2s_main, dim3(NBLK), dim3(NTHR),
                             params, SMEM_BYTES, stream);
}